// Round 7
// baseline (286.647 us; speedup 1.0000x reference)
//
#include <hip/hip_runtime.h>

#define HIMG 256
#define WIMG 256
#define CCH  32
#define JBOX 64
#define BIMG 8
#define HGT  8
#define NBUF 3

// R17: wave-private software pipeline. Zero barriers, counted vmcnt waits,
// register-accumulated outputs (stores OUTSIDE the vmcnt-counted domain --
// R14's counted wait was broken because its per-iter stores incremented
// vmcnt and were drained every iteration).
// - wave = (bj, c); stages its own 2 full rows (2x1KB coalesced DMA) into
//   wave-private LDS; 3 buffers deep; consume reads own LDS only.
// - no __syncthreads anywhere; 24 waves/CU each an independent pipeline.
// - numerics: identical tap/rounding/blend expressions to R14-R16 (passed).
typedef __attribute__((address_space(3))) float lds_f;
typedef const __attribute__((address_space(1))) float glb_f;

__global__ __launch_bounds__(256, 6) void roi_kernel(
    const float* __restrict__ img,     // (B, C, HIMG, WIMG)
    const float* __restrict__ boxes,   // (B, J, 5)
    float* __restrict__ res,           // (B, J, C, HGT, max_w)
    float* __restrict__ mask,          // (B, J, max_w)
    int max_w)
{
    __shared__ float sbuf[4][NBUF][2][WIMG];   // 4 waves x 3 bufs x 2 rows x 1KB = 24KB

    const int d    = blockIdx.x;
    const int b    = d & 7;                // XCD-pinned image (R15: FETCH 76->28MB)
    const int q    = d >> 3;               // 0..511
    const int tid  = threadIdx.x;
    const int wv   = tid >> 6;             // wave 0..3 (uniform)
    const int lane = tid & 63;
    const int c    = (q & 7) * 4 + wv;     // channel 0..31 (wave-uniform)
    const int j    = q >> 3;               // box 0..63
    const int bj   = b * JBOX + j;

    const float left = boxes[bj * 5 + 0];
    const float top  = boxes[bj * 5 + 1];
    const float bw   = boxes[bj * 5 + 2] - left;
    const float bh   = boxes[bj * 5 + 3] - top;

    // width = int32(bw/bh * 8) with f32 ops + truncation (matches numpy).
    const int   width  = (int)(bw / bh * 8.0f);
    const float each_w = bw / ((float)width - 1.0f);
    const float each_h = bh / 7.0f;

    // ---- per-lane x taps for 4 column blocks (h-invariant) ----
    int   lxk[4];
    float wx0k[4], wx1k[4];
    #pragma unroll
    for (int k = 0; k < 4; ++k) {
        const int   i  = 64 * k + lane;
        const float x  = __fadd_rn(__fmul_rn((float)i, each_w), left);
        const int   xf = (int)floorf(x);
        const int   x0 = min(max(xf, 0), WIMG - 1);
        wx1k[k] = (float)(x0 + 1) - x;
        wx0k[k] = x - (float)x0;
        lxk[k]  = min(x0, WIMG - 2);       // lx+1 <= 255, in-row
    }

    const float* chbase = img + (size_t)(b * CCH + c) * (HIMG * WIMG);

    // DMA both rows for step h into buffer bf (wave-private; 64 lanes x 16B
    // = exactly one 1KB image row each; all lanes always active).
    auto dma = [&](int h, int bf) {
        const float yh  = __fadd_rn(__fmul_rn((float)h, each_h), top);
        const int   yfl = (int)floorf(yh);
        const int   ya  = min(max(yfl,     0), HIMG - 1);
        const int   yb  = min(max(yfl + 1, 0), HIMG - 1);
        const float* s0 = chbase + (size_t)ya * WIMG + 4 * lane;
        const float* s1 = chbase + (size_t)yb * WIMG + 4 * lane;
        __builtin_amdgcn_global_load_lds((glb_f*)s0, (lds_f*)&sbuf[wv][bf][0][0], 16, 0, 0);
        __builtin_amdgcn_global_load_lds((glb_f*)s1, (lds_f*)&sbuf[wv][bf][1][0], 16, 0, 0);
    };

    // Consume step h from buffer bf into a float4 accumulator (regs only).
    auto consume = [&](int h, int bf, float4& A) {
        const float yh  = __fadd_rn(__fmul_rn((float)h, each_h), top);
        const int   yfl = (int)floorf(yh);
        const int   ya  = min(max(yfl,     0), HIMG - 1);
        const int   yb  = min(max(yfl + 1, 0), HIMG - 1);
        const float wy1 = (float)yb - yh;
        const float wy0 = yh - (float)ya;
        float vals[4];
        #pragma unroll
        for (int k = 0; k < 4; ++k) {
            const float v00 = sbuf[wv][bf][0][lxk[k]];      // ds_read2_b32
            const float v01 = sbuf[wv][bf][0][lxk[k] + 1];
            const float v10 = sbuf[wv][bf][1][lxk[k]];      // ds_read2_b32
            const float v11 = sbuf[wv][bf][1][lxk[k] + 1];
            const float wa  = wx1k[k] * wy1;
            const float wb_ = wx1k[k] * wy0;
            const float wc_ = wx0k[k] * wy1;
            const float wd_ = wx0k[k] * wy0;
            // identical term order/grouping to R11-R16 (passed absmax):
            vals[k] = v00 * wa + v10 * wb_ + v01 * wc_ + v11 * wd_;
        }
        A.x = vals[0]; A.y = vals[1]; A.z = vals[2]; A.w = vals[3];
    };

    float4 a0, a1, a2, a3, a4, a5, a6, a7;   // 32 VGPR accumulator

    // prologue: 3 steps in flight (6 DMA ops; vmcnt domain = DMA ONLY)
    dma(0, 0);
    dma(1, 1);
    dma(2, 2);
    __builtin_amdgcn_sched_barrier(0);

#define STEP(H, BF, WN, A)                                                    \
    do {                                                                      \
        asm volatile("s_waitcnt vmcnt(" #WN ")" ::: "memory");                \
        __builtin_amdgcn_sched_barrier(0);                                    \
        consume(H, BF, A);                                                    \
        /* own ds_reads must land before DMA overwrites this buffer */        \
        asm volatile("s_waitcnt lgkmcnt(0)" ::: "memory");                    \
        __builtin_amdgcn_sched_barrier(0);                                    \
        if ((H) + 3 < HGT) dma((H) + 3, BF);                                  \
    } while (0)

    STEP(0, 0, 4, a0);   // outstanding {0,1,2}: leave 4 => DMA(0) done
    STEP(1, 1, 4, a1);   // leave {2,3}
    STEP(2, 2, 4, a2);   // leave {3,4}
    STEP(3, 0, 4, a3);   // leave {4,5}
    STEP(4, 1, 4, a4);   // leave {5,6}
    STEP(5, 2, 4, a5);   // leave {6,7}
    STEP(6, 0, 2, a6);   // leave {7}
    STEP(7, 1, 0, a7);   // drain
#undef STEP

    // ---- epilogue: stores (outside any counted-wait domain) ----
    float* rb = res + ((size_t)(bj * CCH + c) * HGT) * (size_t)max_w;

#define STORE_H(H, A)                                                         \
    do {                                                                      \
        const float vals[4] = {A.x, A.y, A.z, A.w};                           \
        _Pragma("unroll")                                                     \
        for (int k = 0; k < 4; ++k) {                                         \
            const int ii = 64 * k + lane;                                     \
            if (ii < max_w)                                                   \
                rb[(size_t)(H) * max_w + ii] = (ii < width) ? vals[k] : 0.0f; \
        }                                                                     \
    } while (0)

    STORE_H(0, a0); STORE_H(1, a1); STORE_H(2, a2); STORE_H(3, a3);
    STORE_H(4, a4); STORE_H(5, a5); STORE_H(6, a6); STORE_H(7, a7);
#undef STORE_H

    if (c == 0) {
        #pragma unroll
        for (int k = 0; k < 4; ++k) {
            const int ii = 64 * k + lane;
            if (ii < max_w)
                mask[(size_t)bj * max_w + ii] = (ii < width) ? 1.0f : 0.0f;
        }
    }
}

extern "C" void kernel_launch(void* const* d_in, const int* in_sizes, int n_in,
                              void* d_out, int out_size, void* d_ws, size_t ws_size,
                              hipStream_t stream) {
    const float* img   = (const float*)d_in[0];
    const float* boxes = (const float*)d_in[1];
    float* out = (float*)d_out;

    const int per_w = BIMG * JBOX * CCH * HGT + BIMG * JBOX;  // 131584
    const int max_w = out_size / per_w;

    float* res  = out;
    float* mask = out + (size_t)BIMG * JBOX * CCH * HGT * max_w;

    const int blocks = BIMG * JBOX * CCH / 4;   // 4096 blocks x 4 waves = 16384 (bj,c) jobs
    roi_kernel<<<blocks, 256, 0, stream>>>(img, boxes, res, mask, max_w);
}

// Round 8
// 152.872 us; speedup vs baseline: 1.8751x; 1.8751x over previous
//
#include <hip/hip_runtime.h>

#define HIMG 256
#define WIMG 256
#define CCH  32
#define JBOX 64
#define BIMG 8
#define HGT  8
#define NBUF 3
#define WCOLS 52   // 52 lanes x 16B = 832B window: cols xs4 .. xs4+207

// R18: R17's barrier-free wave-private DMA pipeline, with the two memory-
// system fixes the R15/R17 contrast isolated:
// 1) CHANNEL-OUTER block order (cg = seq>>6, j = seq&63): resident blocks
//    on an XCD share a handful of 256KB channel planes -> L2 serves the
//    cross-box y-overlap (R15 proved: FETCH 76 -> 28 MB with this order;
//    R17's box-outer order gave 253 MB).
// 2) 832B window DMA (52 active lanes) instead of full 1KB rows.
// Schedule (from R17, the parts that were sound): wave = (box, channel),
// 3-deep buffered global_load_lds, counted vmcnt(4/2/0) with a DMA-ONLY
// vmcnt domain (outputs accumulate in 32 VGPRs, stored in the epilogue;
// R14's bug was per-iter stores polluting the counted wait). Zero barriers.
// Numerics: tap/rounding/blend expressions byte-identical to R11-R17 (all
// passed absmax).
typedef __attribute__((address_space(3))) float lds_f;
typedef const __attribute__((address_space(1))) float glb_f;

__global__ __launch_bounds__(256, 6) void roi_kernel(
    const float* __restrict__ img,     // (B, C, HIMG, WIMG)
    const float* __restrict__ boxes,   // (B, J, 5)
    float* __restrict__ res,           // (B, J, C, HGT, max_w)
    float* __restrict__ mask,          // (B, J, max_w)
    int max_w)
{
    __shared__ float sbuf[4][NBUF][2][208];   // 4 waves x 3 bufs x 2x832B = 19,968B

    const int d    = blockIdx.x;
    const int b    = d & 7;                // XCD-pinned image
    const int seq  = d >> 3;               // 0..511
    const int cg   = seq >> 6;             // 0..7  CHANNEL-OUTER
    const int j    = seq & 63;             // box-inner
    const int bj   = b * JBOX + j;
    const int tid  = threadIdx.x;
    const int wv   = tid >> 6;             // wave 0..3 (uniform)
    const int lane = tid & 63;
    const int c    = cg * 4 + wv;          // channel 0..31 (wave-uniform)

    const float left = boxes[bj * 5 + 0];
    const float top  = boxes[bj * 5 + 1];
    const float bw   = boxes[bj * 5 + 2] - left;
    const float bh   = boxes[bj * 5 + 3] - top;

    // width = int32(bw/bh * 8) with f32 ops + truncation (matches numpy).
    const int   width  = (int)(bw / bh * 8.0f);
    const float each_w = bw / ((float)width - 1.0f);
    const float each_h = bh / 7.0f;

    const int xs  = max((int)floorf(left), 0);   // <= 40
    const int xs4 = xs & ~3;                     // 16B-aligned window start

    // ---- per-lane x taps for active column chunks (h-invariant) ----
    int   lxk[4];
    float wx0k[4], wx1k[4];
    #pragma unroll
    for (int k = 0; k < 4; ++k) {
        if (64 * k < max_w) {              // wave-uniform guard
            const int   i  = 64 * k + lane;
            const float x  = __fadd_rn(__fmul_rn((float)i, each_w), left);
            const int   xf = (int)floorf(x);
            const int   x0 = min(max(xf, 0), WIMG - 1);
            wx1k[k] = (float)(x0 + 1) - x;
            wx0k[k] = x - (float)x0;
            lxk[k]  = min(max(x0 - xs4, 0), 206);   // window pos, +1 <= 207
        }
    }

    const float* chbase = img + (size_t)(b * CCH + c) * (HIMG * WIMG);

    // DMA the two y-rows (832B window each) for step h into buffer bf.
    auto dma = [&](int h, int bf) {
        const float yh  = __fadd_rn(__fmul_rn((float)h, each_h), top);
        const int   yfl = (int)floorf(yh);
        const int   ya  = min(max(yfl,     0), HIMG - 1);
        const int   yb  = min(max(yfl + 1, 0), HIMG - 1);
        if (lane < WCOLS) {                // src in-bounds: xs4+207 <= 247
            const float* s0 = chbase + (size_t)ya * WIMG + xs4 + 4 * lane;
            const float* s1 = chbase + (size_t)yb * WIMG + xs4 + 4 * lane;
            __builtin_amdgcn_global_load_lds((glb_f*)s0, (lds_f*)&sbuf[wv][bf][0][0], 16, 0, 0);
            __builtin_amdgcn_global_load_lds((glb_f*)s1, (lds_f*)&sbuf[wv][bf][1][0], 16, 0, 0);
        }
    };

    // Consume step h from buffer bf into a float4 accumulator (regs only).
    auto consume = [&](int h, int bf, float4& A) {
        const float yh  = __fadd_rn(__fmul_rn((float)h, each_h), top);
        const int   yfl = (int)floorf(yh);
        const int   ya  = min(max(yfl,     0), HIMG - 1);
        const int   yb  = min(max(yfl + 1, 0), HIMG - 1);
        const float wy1 = (float)yb - yh;
        const float wy0 = yh - (float)ya;
        float vals[4] = {0.0f, 0.0f, 0.0f, 0.0f};
        #pragma unroll
        for (int k = 0; k < 4; ++k) {
            if (64 * k < max_w) {          // wave-uniform guard
                const float v00 = sbuf[wv][bf][0][lxk[k]];      // ds_read2_b32
                const float v01 = sbuf[wv][bf][0][lxk[k] + 1];
                const float v10 = sbuf[wv][bf][1][lxk[k]];      // ds_read2_b32
                const float v11 = sbuf[wv][bf][1][lxk[k] + 1];
                const float wa  = wx1k[k] * wy1;
                const float wb_ = wx1k[k] * wy0;
                const float wc_ = wx0k[k] * wy1;
                const float wd_ = wx0k[k] * wy0;
                // identical term order/grouping to R11-R17 (passed absmax):
                vals[k] = v00 * wa + v10 * wb_ + v01 * wc_ + v11 * wd_;
            }
        }
        A.x = vals[0]; A.y = vals[1]; A.z = vals[2]; A.w = vals[3];
    };

    float4 a0, a1, a2, a3, a4, a5, a6, a7;   // 32 VGPR accumulator

    // prologue: 3 steps in flight (6 DMA ops; vmcnt domain = DMA ONLY)
    dma(0, 0);
    dma(1, 1);
    dma(2, 2);
    __builtin_amdgcn_sched_barrier(0);

#define STEP(H, BF, WN, A)                                                    \
    do {                                                                      \
        asm volatile("s_waitcnt vmcnt(" #WN ")" ::: "memory");                \
        __builtin_amdgcn_sched_barrier(0);                                    \
        consume(H, BF, A);                                                    \
        /* own ds_reads retired before DMA may overwrite this buffer */       \
        asm volatile("s_waitcnt lgkmcnt(0)" ::: "memory");                    \
        __builtin_amdgcn_sched_barrier(0);                                    \
        if ((H) + 3 < HGT) dma((H) + 3, BF);                                  \
    } while (0)

    STEP(0, 0, 4, a0);   // out {0,1,2}: leave 4 => pair(0) done
    STEP(1, 1, 4, a1);
    STEP(2, 2, 4, a2);
    STEP(3, 0, 4, a3);
    STEP(4, 1, 4, a4);
    STEP(5, 2, 4, a5);   // last refill was at STEP(4) (h=7)
    STEP(6, 0, 2, a6);   // out {6,7}: leave 2 => pair(6) done
    STEP(7, 1, 0, a7);   // drain
#undef STEP

    // ---- epilogue: all stores outside the counted-wait domain ----
    float* rb = res + ((size_t)(bj * CCH + c) * HGT) * (size_t)max_w;

#define STORE_H(H, A)                                                         \
    do {                                                                      \
        const float vals[4] = {A.x, A.y, A.z, A.w};                           \
        _Pragma("unroll")                                                     \
        for (int k = 0; k < 4; ++k) {                                         \
            const int ii = 64 * k + lane;                                     \
            if (ii < max_w)                                                   \
                rb[(size_t)(H) * max_w + ii] = (ii < width) ? vals[k] : 0.0f; \
        }                                                                     \
    } while (0)

    STORE_H(0, a0); STORE_H(1, a1); STORE_H(2, a2); STORE_H(3, a3);
    STORE_H(4, a4); STORE_H(5, a5); STORE_H(6, a6); STORE_H(7, a7);
#undef STORE_H

    if (c == 0) {
        #pragma unroll
        for (int k = 0; k < 4; ++k) {
            const int ii = 64 * k + lane;
            if (ii < max_w)
                mask[(size_t)bj * max_w + ii] = (ii < width) ? 1.0f : 0.0f;
        }
    }
}

extern "C" void kernel_launch(void* const* d_in, const int* in_sizes, int n_in,
                              void* d_out, int out_size, void* d_ws, size_t ws_size,
                              hipStream_t stream) {
    const float* img   = (const float*)d_in[0];
    const float* boxes = (const float*)d_in[1];
    float* out = (float*)d_out;

    const int per_w = BIMG * JBOX * CCH * HGT + BIMG * JBOX;  // 131584
    const int max_w = out_size / per_w;

    float* res  = out;
    float* mask = out + (size_t)BIMG * JBOX * CCH * HGT * max_w;

    const int blocks = BIMG * JBOX * CCH / 4;   // 4096 = (cg, j) per XCD-image
    roi_kernel<<<blocks, 256, 0, stream>>>(img, boxes, res, mask, max_w);
}